// Round 6
// baseline (556.157 us; speedup 1.0000x reference)
//
#include <hip/hip_runtime.h>
#include <math.h>

// Problem constants
#define KCODES 1024
#define DDIM   64

// Output layout (floats), concatenated in reference return order:
// z_q_out [16,64,64,64], idx_out [16,64,64], emb_new [64,1024],
// emb_ema_new [64,1024], counts_ema_new [1024]
constexpr size_t O_ZQ  = 0;
constexpr size_t O_IDX = 4194304;
constexpr size_t O_EMB = O_IDX + 65536;   // 4259840
constexpr size_t O_EMA = O_EMB + 65536;   // 4325376
constexpr size_t O_CEN = O_EMA + 65536;   // 4390912

// Workspace layout (float offsets)
constexpr size_t W_UPD   = 0;              // [K][D] segment-sum accumulator
constexpr size_t W_CNT   = 65536;          // [K] histogram
constexpr size_t W_ENORM = W_CNT + 1024;   // [K] ||e_k||^2
constexpr size_t W_EMBT  = W_ENORM + 1024; // [K][D] transposed codebook

// ---------------------------------------------------------------------------
// K1: LDS-tiled transpose emb[D][K] -> embT[K][D], eNorm, zero W_UPD/W_CNT.
// 16 blocks; block g handles codes k0 = g*64 .. k0+63.
__global__ __launch_bounds__(256) void vq_prep(const float* __restrict__ emb,
                                               float* __restrict__ ws) {
  __shared__ float t_lds[64 * 65];          // [d][k] padded (+1)
  const int tid = threadIdx.x;
  const int g   = blockIdx.x;
  const int k0  = g * 64;

  #pragma unroll
  for (int it = 0; it < 16; ++it) {
    const int idx = tid + it * 256;         // 0..4095
    const int d   = idx >> 6;
    const int kq  = idx & 63;
    t_lds[d * 65 + kq] = emb[d * KCODES + k0 + kq];
  }
  __syncthreads();

  #pragma unroll
  for (int it = 0; it < 16; ++it) {
    const int idx = tid + it * 256;
    const int k   = idx >> 6;
    const int d   = idx & 63;
    ws[W_EMBT + (size_t)(k0 + k) * 64 + d] = t_lds[d * 65 + k];
  }

  if (tid < 64) {
    const int k = tid;
    float s = 0.f;
    #pragma unroll
    for (int d = 0; d < DDIM; ++d) {
      const float v = t_lds[d * 65 + k];
      s = fmaf(v, v, s);
    }
    ws[W_ENORM + k0 + k] = s;
  }

  float4* u4 = (float4*)(ws + W_UPD);
  #pragma unroll
  for (int j = 0; j < 4; ++j) u4[g * 1024 + tid + j * 256] = float4{0.f, 0.f, 0.f, 0.f};
  if (tid < 64) ws[W_CNT + k0 + tid] = 0.f;
}

// ---------------------------------------------------------------------------
// K2: barrier-free distance scan.
// 1024 blocks x 256 threads. Block covers 64 rows; lane = row. Each of the 4
// waves scans a 256-code quarter; e-row address is wave-uniform (loop index)
// -> scalarizes to s_load against const __restrict__ embT (worst case:
// uniform-address vector loads, still cheap). z[64] lives in VGPRs; no LDS
// and no __syncthreads in the hot loop.
__global__ __launch_bounds__(256, 3) void vq_main(
    const float* __restrict__ z_e,
    const float* __restrict__ embT,   // ws + W_EMBT  [K][D]
    const float* __restrict__ eN,     // ws + W_ENORM [K]
    float* __restrict__ upd,          // ws + W_UPD   [K][D]
    float* __restrict__ cnt,          // ws + W_CNT   [K]
    float* __restrict__ out) {
  __shared__ float z_lds[64 * 65];    // [d][row] padded: epilogue transpose
  __shared__ float s_v[256];          // merge values
  __shared__ int   s_i[256];          // merge indices
  __shared__ int   bidx[64];

  const int tid  = threadIdx.x;
  const int bid  = blockIdx.x;
  const int wv   = tid >> 6;
  const int lane = tid & 63;          // = row within block (main loop)

  const int n0  = bid * 64;           // block's first row id
  const int b   = n0 >> 12;
  const int hw0 = n0 & 4095;
  const size_t zbase = (size_t)b * 262144 + (size_t)hw0;

  // ---- stage z tile [64 d][64 rows] into LDS (coalesced), then regs ----
  #pragma unroll
  for (int it = 0; it < 16; ++it) {
    const int idx = tid + it * 256;   // 0..4095
    const int d   = idx >> 6;
    const int r   = idx & 63;
    z_lds[d * 65 + r] = z_e[zbase + (size_t)d * 4096 + r];
  }
  __syncthreads();

  float z[DDIM];
  #pragma unroll
  for (int d = 0; d < DDIM; ++d) z[d] = z_lds[d * 65 + lane];

  // ---- barrier-free argmin scan over this wave's code quarter ----
  float minval = INFINITY;
  int   minidx = 0;
  const int k0 = wv * 256;

  #pragma unroll 1
  for (int k = k0; k < k0 + 256; ++k) {
    const float* __restrict__ er = embT + (size_t)k * 64;  // wave-uniform
    float a0 = 0.f, a1 = 0.f, a2 = 0.f, a3 = 0.f;
    #pragma unroll
    for (int d = 0; d < DDIM; d += 4) {
      a0 = fmaf(z[d + 0], er[d + 0], a0);
      a1 = fmaf(z[d + 1], er[d + 1], a1);
      a2 = fmaf(z[d + 2], er[d + 2], a2);
      a3 = fmaf(z[d + 3], er[d + 3], a3);
    }
    const float dot = (a0 + a1) + (a2 + a3);
    const float val = fmaf(-2.f, dot, eN[k]);   // ||e||^2 - 2 z.e
    if (val < minval) { minval = val; minidx = k; }  // ascending k: first min
  }

  // ---- merge the 4 wave-quarters per row ----
  s_v[wv * 64 + lane] = minval;
  s_i[wv * 64 + lane] = minidx;
  __syncthreads();

  if (tid < 64) {
    const int row = tid;
    float bv = s_v[row];
    int   bi = s_i[row];
    #pragma unroll
    for (int w = 1; w < 4; ++w) {       // ascending code ranges: strict <
      const float v = s_v[w * 64 + row];
      if (v < bv) { bv = v; bi = s_i[w * 64 + row]; }
    }
    bidx[row] = bi;
    out[O_IDX + n0 + row] = (float)bi;
    atomicAdd(cnt + bi, 1.0f);
  }
  __syncthreads();

  // ---- epilogue A: z_q = z + (e - z); coalesced stores over rows ----
  {
    const int row  = tid & 63;
    const int dgrp = tid >> 6;          // 4 groups x 16 d
    const int code = bidx[row];
    const float* __restrict__ erow = embT + (size_t)code * 64;
    #pragma unroll
    for (int i = 0; i < 16; ++i) {
      const int d = dgrp * 16 + i;
      const float zv = z_lds[d * 65 + row];
      out[O_ZQ + zbase + (size_t)d * 4096 + row] = zv + (erow[d] - zv);
    }
  }

  // ---- epilogue B: segment-sum; one coalesced atomic per row ----
  {
    // lane = d; z_lds read addr lane*65+row -> banks (lane+row)%32: conflict-free
    #pragma unroll 4
    for (int rr = 0; rr < 16; ++rr) {
      const int row  = wv * 16 + rr;
      const int code = bidx[row];
      atomicAdd(upd + (size_t)code * 64 + lane, z_lds[lane * 65 + row]);
    }
  }
}

// ---------------------------------------------------------------------------
// K3: EMA updates + normalization. Each block redundantly reduces n.
__global__ __launch_bounds__(256) void vq_final(const float* __restrict__ emb_ema,
                                                const float* __restrict__ counts_ema,
                                                const float* __restrict__ ws,
                                                float* __restrict__ out) {
  __shared__ float red[256];
  const int tid = threadIdx.x;
  const float* cnt = ws + W_CNT;

  float psum = 0.f;
  for (int t = tid; t < KCODES; t += 256) {
    const float ce  = counts_ema[t];
    const float cen = ce + 0.01f * (cnt[t] - ce);
    psum += cen;
    if (blockIdx.x == 0) out[O_CEN + t] = cen;
  }
  red[tid] = psum;
  __syncthreads();
  #pragma unroll
  for (int s = 128; s > 0; s >>= 1) {
    if (tid < s) red[tid] += red[tid + s];
    __syncthreads();
  }
  const float nsum = red[0];

  const int i = blockIdx.x * 256 + tid;   // 0..65535 over [D][K]
  const int d = i >> 10;
  const int k = i & 1023;

  const float ce  = counts_ema[k];
  const float cen = ce + 0.01f * (cnt[k] - ce);
  const float norm = (cen + 1e-5f) / (nsum + (float)KCODES * 1e-5f) * nsum;

  const float ema     = emb_ema[i];
  const float ema_new = ema + 0.01f * (ws[W_UPD + (size_t)k * 64 + d] - ema);
  out[O_EMA + i] = ema_new;
  out[O_EMB + i] = ema_new / norm;
}

// ---------------------------------------------------------------------------
extern "C" void kernel_launch(void* const* d_in, const int* in_sizes, int n_in,
                              void* d_out, int out_size, void* d_ws, size_t ws_size,
                              hipStream_t stream) {
  const float* z_e        = (const float*)d_in[0];
  const float* emb        = (const float*)d_in[1];
  const float* emb_ema    = (const float*)d_in[2];
  const float* counts_ema = (const float*)d_in[3];
  float* out = (float*)d_out;
  float* ws  = (float*)d_ws;

  vq_prep<<<16, 256, 0, stream>>>(emb, ws);
  vq_main<<<1024, 256, 0, stream>>>(z_e, ws + W_EMBT, ws + W_ENORM,
                                    ws + W_UPD, ws + W_CNT, out);
  vq_final<<<256, 256, 0, stream>>>(emb_ema, counts_ema, ws, out);
}

// Round 7
// 192.994 us; speedup vs baseline: 2.8817x; 2.8817x over previous
//
#include <hip/hip_runtime.h>
#include <math.h>

// Problem constants
#define KCODES 1024
#define DDIM   64

// Output layout (floats), concatenated in reference return order:
// z_q_out [16,64,64,64], idx_out [16,64,64], emb_new [64,1024],
// emb_ema_new [64,1024], counts_ema_new [1024]
constexpr size_t O_ZQ  = 0;
constexpr size_t O_IDX = 4194304;
constexpr size_t O_EMB = O_IDX + 65536;   // 4259840
constexpr size_t O_EMA = O_EMB + 65536;   // 4325376
constexpr size_t O_CEN = O_EMA + 65536;   // 4390912

// Workspace layout (float offsets)
constexpr size_t W_UPD   = 0;              // [K][D] segment-sum accumulator
constexpr size_t W_CNT   = 65536;          // [K] histogram
constexpr size_t W_ENORM = W_CNT + 1024;   // [K] ||e_k||^2
constexpr size_t W_EMBT  = W_ENORM + 1024; // [K][D] transposed codebook

// ---------------------------------------------------------------------------
// K1: LDS-tiled transpose emb[D][K] -> embT[K][D], eNorm, zero W_UPD/W_CNT.
// 16 blocks; block g handles codes k0 = g*64 .. k0+63.
__global__ __launch_bounds__(256) void vq_prep(const float* __restrict__ emb,
                                               float* __restrict__ ws) {
  __shared__ float t_lds[64 * 65];          // [d][k] padded (+1)
  const int tid = threadIdx.x;
  const int g   = blockIdx.x;
  const int k0  = g * 64;

  #pragma unroll
  for (int it = 0; it < 16; ++it) {
    const int idx = tid + it * 256;         // 0..4095
    const int d   = idx >> 6;
    const int kq  = idx & 63;
    t_lds[d * 65 + kq] = emb[d * KCODES + k0 + kq];
  }
  __syncthreads();

  #pragma unroll
  for (int it = 0; it < 16; ++it) {
    const int idx = tid + it * 256;
    const int k   = idx >> 6;
    const int d   = idx & 63;
    ws[W_EMBT + (size_t)(k0 + k) * 64 + d] = t_lds[d * 65 + k];
  }

  if (tid < 64) {
    const int k = tid;
    float s = 0.f;
    #pragma unroll
    for (int d = 0; d < DDIM; ++d) {
      const float v = t_lds[d * 65 + k];
      s = fmaf(v, v, s);
    }
    ws[W_ENORM + k0 + k] = s;
  }

  float4* u4 = (float4*)(ws + W_UPD);
  #pragma unroll
  for (int j = 0; j < 4; ++j) u4[g * 1024 + tid + j * 256] = float4{0.f, 0.f, 0.f, 0.f};
  if (tid < 64) ws[W_CNT + k0 + tid] = 0.f;
}

// ---------------------------------------------------------------------------
// K2: tiled distance GEMM + argmin + fused epilogue, sized for 4 blocks/CU.
// 1024 blocks x 256 threads; block = 64 rows x full K.
// Thread map: colgrp = tid&31, rowgrp = tid>>5; per-thread 8 rows x 8 codes
// (codes colgrp*4 + q*128 + j within a 256-code chunk) -> acc[8][8] = 64 VGPRs.
// z-tile [64d][64r] pad 68 (17.4 KB, b128-aligned, 2-way banks); e-tile
// 16d x 256 codes (16 KB) single-buffered; ~34 KB LDS total -> 4 blocks/CU.
// Argmin merged in-wave via 5-step butterfly over lane bits 0..4.
#define ZP 68
__global__ __launch_bounds__(256, 4) void vq_main(
    const float* __restrict__ z_e,
    const float* __restrict__ emb,    // native [D][K]
    const float* __restrict__ embT,   // ws + W_EMBT  [K][D] (epilogue A)
    const float* __restrict__ eN,     // ws + W_ENORM [K]
    float* __restrict__ upd,          // ws + W_UPD   [K][D]
    float* __restrict__ cnt,          // ws + W_CNT   [K]
    float* __restrict__ out) {
  __shared__ float z_lds[DDIM * ZP];  // [d][row] padded
  __shared__ float e_lds[16 * 256];   // [dp][code]
  __shared__ int   bidx[64];

  const int tid    = threadIdx.x;
  const int bid    = blockIdx.x;
  const int wv     = tid >> 6;
  const int lane   = tid & 63;
  const int colgrp = tid & 31;        // 0..31 (lane bits 0..4)
  const int rowgrp = tid >> 5;        // 0..7
  const int r0     = rowgrp * 8;
  const int c0t    = colgrp * 4;

  const int n0  = bid * 64;           // block's first row id
  const int b   = n0 >> 12;
  const int hw0 = n0 & 4095;          // multiple of 64
  const size_t zbase = (size_t)b * 262144 + (size_t)hw0;

  // ---- stage z tile [64][64] (coalesced 256B segments per instr) ----
  {
    const float4* z4 = (const float4*)(z_e + zbase);   // + d*1024 (float4)
    #pragma unroll
    for (int it = 0; it < 4; ++it) {
      const int f  = tid + it * 256;   // 0..1023
      const int d  = f >> 4;           // 0..63
      const int r4 = f & 15;           // float4 within row
      const float4 v = z4[(size_t)d * 1024 + r4];
      *(float4*)(z_lds + d * ZP + r4 * 4) = v;
    }
  }

  float minval[8];
  int   minidx[8];
  #pragma unroll
  for (int i = 0; i < 8; ++i) { minval[i] = INFINITY; minidx[i] = 0; }

  #pragma unroll 1
  for (int chunk = 0; chunk < 4; ++chunk) {
    const int c0 = chunk * 256;

    float acc[8][8];
    #pragma unroll
    for (int i = 0; i < 8; ++i)
      #pragma unroll
      for (int j = 0; j < 8; ++j) acc[i][j] = 0.f;

    #pragma unroll 1
    for (int pp = 0; pp < 4; ++pp) {
      const int dstart = pp * 16;
      __syncthreads();   // previous phase's e_lds reads done
      // ---- stage e tile [16][256] <- emb[dstart+dp][c0..c0+255] ----
      {
        const float4* eg = (const float4*)emb;
        #pragma unroll
        for (int it = 0; it < 4; ++it) {
          const int dp = it * 4 + wv;
          const float4 v = eg[(size_t)(dstart + dp) * 256 + (c0 >> 2) + lane];
          *(float4*)(e_lds + dp * 256 + lane * 4) = v;
        }
      }
      __syncthreads();

      #pragma unroll 4
      for (int dp = 0; dp < 16; ++dp) {
        const int d = dstart + dp;
        float zf[8], ef[8];
        const float4 za = *(const float4*)(z_lds + d * ZP + r0);
        const float4 zb = *(const float4*)(z_lds + d * ZP + r0 + 4);
        zf[0]=za.x; zf[1]=za.y; zf[2]=za.z; zf[3]=za.w;
        zf[4]=zb.x; zf[5]=zb.y; zf[6]=zb.z; zf[7]=zb.w;
        const float4 e0 = *(const float4*)(e_lds + dp * 256 + c0t);
        const float4 e1 = *(const float4*)(e_lds + dp * 256 + c0t + 128);
        ef[0]=e0.x; ef[1]=e0.y; ef[2]=e0.z; ef[3]=e0.w;
        ef[4]=e1.x; ef[5]=e1.y; ef[6]=e1.z; ef[7]=e1.w;
        #pragma unroll
        for (int i = 0; i < 8; ++i)
          #pragma unroll
          for (int j = 0; j < 8; ++j)
            acc[i][j] = fmaf(zf[i], ef[j], acc[i][j]);
      }
    }

    // ---- fold chunk into running argmin (index-ascending order) ----
    float en[8];
    {
      const float4 v0 = *(const float4*)(eN + c0 + c0t);
      const float4 v1 = *(const float4*)(eN + c0 + c0t + 128);
      en[0]=v0.x; en[1]=v0.y; en[2]=v0.z; en[3]=v0.w;
      en[4]=v1.x; en[5]=v1.y; en[6]=v1.z; en[7]=v1.w;
    }
    #pragma unroll
    for (int i = 0; i < 8; ++i) {
      #pragma unroll
      for (int q = 0; q < 2; ++q) {
        #pragma unroll
        for (int j = 0; j < 4; ++j) {
          const float val = fmaf(-2.f, acc[i][q * 4 + j], en[q * 4 + j]);
          if (val < minval[i]) {
            minval[i] = val;
            minidx[i] = c0 + c0t + q * 128 + j;
          }
        }
      }
    }
  }

  // ---- cross-colgrp argmin: butterfly over lane bits 0..4 ----
  #pragma unroll
  for (int i = 0; i < 8; ++i) {
    float v = minval[i];
    int  ix = minidx[i];
    #pragma unroll
    for (int m = 1; m < 32; m <<= 1) {
      const float v2 = __shfl_xor(v, m, 64);
      const int   i2 = __shfl_xor(ix, m, 64);
      if (v2 < v || (v2 == v && i2 < ix)) { v = v2; ix = i2; }
    }
    minidx[i] = ix;   // lanes within each 32-half agree
  }

  if (colgrp == 0) {  // 2 lanes per wave, 8 writers total, 8 rows each
    #pragma unroll
    for (int i = 0; i < 8; ++i) {
      const int row = r0 + i;
      const int bi  = minidx[i];
      bidx[row] = bi;
      out[O_IDX + n0 + row] = (float)bi;
      atomicAdd(cnt + bi, 1.0f);
    }
  }
  __syncthreads();

  // ---- epilogue A: z_q = z + (e - z); coalesced stores over rows ----
  {
    const int row  = tid & 63;
    const int dgrp = tid >> 6;          // 4 groups x 16 d
    const int code = bidx[row];
    const float4* er4 = (const float4*)(embT + (size_t)code * 64);
    #pragma unroll
    for (int q = 0; q < 4; ++q) {
      const float4 e4 = er4[dgrp * 4 + q];
      const float ev[4] = {e4.x, e4.y, e4.z, e4.w};
      #pragma unroll
      for (int x = 0; x < 4; ++x) {
        const int d = dgrp * 16 + q * 4 + x;
        const float zv = z_lds[d * ZP + row];
        out[O_ZQ + zbase + (size_t)d * 4096 + row] = zv + (ev[x] - zv);
      }
    }
  }

  // ---- epilogue B: segment-sum; one coalesced atomic instruction per row ----
  {
    #pragma unroll 4
    for (int rr = 0; rr < 16; ++rr) {
      const int row  = wv * 16 + rr;
      const int code = bidx[row];
      atomicAdd(upd + (size_t)code * 64 + lane, z_lds[lane * ZP + row]);
    }
  }
}

// ---------------------------------------------------------------------------
// K3: EMA updates + normalization. Each block redundantly reduces n.
__global__ __launch_bounds__(256) void vq_final(const float* __restrict__ emb_ema,
                                                const float* __restrict__ counts_ema,
                                                const float* __restrict__ ws,
                                                float* __restrict__ out) {
  __shared__ float red[256];
  const int tid = threadIdx.x;
  const float* cnt = ws + W_CNT;

  float psum = 0.f;
  for (int t = tid; t < KCODES; t += 256) {
    const float ce  = counts_ema[t];
    const float cen = ce + 0.01f * (cnt[t] - ce);
    psum += cen;
    if (blockIdx.x == 0) out[O_CEN + t] = cen;
  }
  red[tid] = psum;
  __syncthreads();
  #pragma unroll
  for (int s = 128; s > 0; s >>= 1) {
    if (tid < s) red[tid] += red[tid + s];
    __syncthreads();
  }
  const float nsum = red[0];

  const int i = blockIdx.x * 256 + tid;   // 0..65535 over [D][K]
  const int d = i >> 10;
  const int k = i & 1023;

  const float ce  = counts_ema[k];
  const float cen = ce + 0.01f * (cnt[k] - ce);
  const float norm = (cen + 1e-5f) / (nsum + (float)KCODES * 1e-5f) * nsum;

  const float ema     = emb_ema[i];
  const float ema_new = ema + 0.01f * (ws[W_UPD + (size_t)k * 64 + d] - ema);
  out[O_EMA + i] = ema_new;
  out[O_EMB + i] = ema_new / norm;
}

// ---------------------------------------------------------------------------
extern "C" void kernel_launch(void* const* d_in, const int* in_sizes, int n_in,
                              void* d_out, int out_size, void* d_ws, size_t ws_size,
                              hipStream_t stream) {
  const float* z_e        = (const float*)d_in[0];
  const float* emb        = (const float*)d_in[1];
  const float* emb_ema    = (const float*)d_in[2];
  const float* counts_ema = (const float*)d_in[3];
  float* out = (float*)d_out;
  float* ws  = (float*)d_ws;

  vq_prep<<<16, 256, 0, stream>>>(emb, ws);
  vq_main<<<1024, 256, 0, stream>>>(z_e, emb, ws + W_EMBT, ws + W_ENORM,
                                    ws + W_UPD, ws + W_CNT, out);
  vq_final<<<256, 256, 0, stream>>>(emb_ema, counts_ema, ws, out);
}